// Round 13
// baseline (72.002 us; speedup 1.0000x reference)
//
#include <hip/hip_runtime.h>
#include <hip/hip_bf16.h>

#define BB 64
#define NN 96
#define FF 16
#define HH 128
#define KK 64
#define LL 3
#define CUTOFF_F 10.0f
#define GAMMA_F 10.0f

#define W3_BLOCKS 99
#define WA2_CP 12
#define WO1_CP 4
#define CNT_BLOCKS BB

// ---------------------------------------------------------------------------
// pre_kernel (unchanged from R12):
//   [0,99):    W3 rows k-quad-interleaved: W3i[l][(kk>>2)*128+h][kk&3]; c3.
//   [99,111):  Wa2i = k-quad-interleaved Wa2
//   [111,115): Wo1i = k-quad-interleaved Wo1
//   [115,179): cnt[b]; zero out[b]
// ---------------------------------------------------------------------------
__global__ __launch_bounds__(256) void pre_kernel(
    const float* __restrict__ Wrbf, const float* __restrict__ brbf,
    const float* __restrict__ Wpair, const float* __restrict__ bpair,
    const float* __restrict__ Wa1, const float* __restrict__ Wa2,
    const float* __restrict__ Wo1,
    const int* __restrict__ batch,
    float* __restrict__ W3i, float* __restrict__ c3,
    float* __restrict__ Wa2i, float* __restrict__ Wo1i,
    float* __restrict__ cnt, float* __restrict__ out)
{
    const int bid = blockIdx.x;
    const int tid = threadIdx.x;
    if (bid < W3_BLOCKS) {
        __shared__ float sW2[2][HH];
        const int l    = bid / 33;
        const int r0   = (bid % 33) * 2;
        const int half = tid >> 7;
        const int h    = tid & 127;
        const int kk   = r0 + half;       // 0..65 (65 inactive)
        const bool active = (kk <= KK);
        if (active) {
            const float* Wp = Wpair + l * HH * HH + h;
            const float* arow;
            float acc;
            if (kk < KK) { arow = Wrbf + (l * KK + kk) * HH; acc = 0.f; }
            else         { arow = brbf + l * HH;             acc = bpair[l * HH + h]; }
            #pragma unroll 8
            for (int m = 0; m < HH; ++m) acc += arow[m] * Wp[m * HH];
            sW2[half][h] = acc;
        }
        __syncthreads();
        if (active) {
            const float* Wa = Wa1 + l * HH * HH + h;
            const float* row = sW2[half];
            float a3 = 0.f;
            #pragma unroll 8
            for (int m = 0; m < HH; ++m) a3 += row[m] * Wa[m * HH];
            if (kk < KK)
                W3i[l * KK * HH + (((kk >> 2) * HH + h) << 2) + (kk & 3)] = a3;
            else
                c3[l * HH + h] = a3;
        }
    } else if (bid < W3_BLOCKS + WA2_CP + WO1_CP) {
        int ci = bid - W3_BLOCKS;
        const float* src;
        float* dst;
        if (ci < WA2_CP) { src = Wa2 + ci * 4096; dst = Wa2i + ci * 4096; }
        else             { src = Wo1 + (ci - WA2_CP) * 4096; dst = Wo1i + (ci - WA2_CP) * 4096; }
        for (int e = tid; e < 4096; e += 256) {
            int k = e >> 7, h = e & 127;
            dst[(((k >> 2) * HH + h) << 2) + (k & 3)] = src[e];
        }
    } else {
        int b = bid - (W3_BLOCKS + WA2_CP + WO1_CP);
        __shared__ int c[4];
        bool v = (tid < NN) && (batch[b * NN + tid] != -1);
        unsigned long long m = __ballot(v);
        if ((tid & 63) == 0) c[tid >> 6] = __popcll(m);
        __syncthreads();
        if (tid == 0) {
            cnt[b] = (float)(c[0] + c[1] + c[2] + c[3]);
            out[b] = 0.f;
        }
    }
}

// ---------------------------------------------------------------------------
// chain_kernel: AT=12, 256 thr, grid 512 = exactly 2 blocks/CU (no tail).
// Thread tile: 1 channel (hh) x 6 atoms (half=tid>>7 -> atoms 6half..6half+5).
// Weights stream through a 4-slot x 16KB LDS ring (global_load_lds), counted
// vmcnt(8) + ONE raw s_barrier per phase (wait BEFORE barrier publishes all
// waves' loads; stage AFTER barrier overwrites a provably-dead slot; 4 slots
// give each chunk 3 phases of flight). No mid-loop vmcnt(0) drains.
// ---------------------------------------------------------------------------
#define AT 12
#define CHF 4096              // floats per 16KB chunk (32 k x 128 ch quad-interleaved)
#define SSW 64                // sST row stride
#define TBW 128               // tbT row stride

typedef const __attribute__((address_space(1))) void* gp1_t;
typedef __attribute__((address_space(3))) void* lp3_t;

__device__ __forceinline__ void stage16k(const float* g, float* lds, int tid)
{
    const int lane = tid & 63, wvq = tid >> 6;
    #pragma unroll
    for (int j = 0; j < 4; ++j) {
        const int base = j * 256 + wvq * 64;           // float4 units
        __builtin_amdgcn_global_load_lds((gp1_t)(g + (size_t)(base + lane) * 4),
                                         (lp3_t)(lds + (size_t)base * 4), 16, 0, 0);
    }
}

// phase boundary: publish my loads for the NEXT chunk (vmcnt<=N), flush LDS
// writes (lgkm), then barrier -> all waves' data visible. Stage goes AFTER.
#define BND(VM) do {                                                        \
    asm volatile("s_waitcnt vmcnt(" VM ") lgkmcnt(0)" ::: "memory");        \
    __builtin_amdgcn_s_barrier();                                           \
    __builtin_amdgcn_sched_barrier(0);                                      \
} while (0)

__device__ __forceinline__ float silu1(float v) { return v / (1.f + __expf(-v)); }

// one 16KB chunk (32 k) of a GEMM: 8 quad-groups; 6 atoms; 24 FMA per group
#define GEMMQ6(ACC, WBP, SRC, KB) do {                                      \
    _Pragma("unroll")                                                       \
    for (int g5 = 0; g5 < 8; ++g5) {                                        \
        float4 w4 = *(const float4*)&(WBP)[(g5 * HH + hh) << 2];            \
        float4 u0 = *(const float4*)&SRC[at0 + 0][(KB) + g5 * 4];           \
        float4 u1 = *(const float4*)&SRC[at0 + 1][(KB) + g5 * 4];           \
        float4 u2 = *(const float4*)&SRC[at0 + 2][(KB) + g5 * 4];           \
        float4 u3 = *(const float4*)&SRC[at0 + 3][(KB) + g5 * 4];           \
        float4 u4 = *(const float4*)&SRC[at0 + 4][(KB) + g5 * 4];           \
        float4 u5 = *(const float4*)&SRC[at0 + 5][(KB) + g5 * 4];           \
        ACC[0] += w4.x*u0.x + w4.y*u0.y + w4.z*u0.z + w4.w*u0.w;            \
        ACC[1] += w4.x*u1.x + w4.y*u1.y + w4.z*u1.z + w4.w*u1.w;            \
        ACC[2] += w4.x*u2.x + w4.y*u2.y + w4.z*u2.z + w4.w*u2.w;            \
        ACC[3] += w4.x*u3.x + w4.y*u3.y + w4.z*u3.z + w4.w*u3.w;            \
        ACC[4] += w4.x*u4.x + w4.y*u4.y + w4.z*u4.z + w4.w*u4.w;            \
        ACC[5] += w4.x*u5.x + w4.y*u5.y + w4.z*u5.z + w4.w*u5.w;            \
    }                                                                       \
} while (0)

__global__ __launch_bounds__(256, 2) void chain_kernel(
    const float* __restrict__ X, const float* __restrict__ R,
    const float* __restrict__ We, const float* __restrict__ be,
    const float* __restrict__ ba1, const float* __restrict__ ba2,
    const float* __restrict__ bo1, const float* __restrict__ Wo2,
    const float* __restrict__ bo2, const float* __restrict__ W3i,
    const float* __restrict__ Wa2i, const float* __restrict__ Wo1i,
    const float* __restrict__ c3, const float* __restrict__ cnt,
    float* __restrict__ out)
{
    __shared__ __align__(16) float wb[4][CHF];     // 64KB weight ring
    __shared__ __align__(16) float sST[AT][SSW];   // 3KB S, atom-major (persists)
    __shared__ __align__(16) float tbT[AT][TBW];   // 6KB t / h (sD/sRf alias early)
    __shared__ __align__(16) float sX[FF][AT];     // 0.75KB
    __shared__ float po[4][6];

    const int tid  = threadIdx.x;
    const int hh   = tid & 127;          // channel
    const int half = tid >> 7;           // atom half
    const int wv   = tid >> 6;           // wave 0..3
    const int at0  = half * 6;           // this thread's atoms at0..at0+5
    const int a0   = blockIdx.x * AT;    // 96 % 12 == 0 -> block within one molecule
    const int b    = a0 / NN;
    const int lbase = a0 - b * NN;       // molecule-local first atom
    const float cb = cnt[b];
    const int nv   = (int)cb;            // valid atoms = molecule-local prefix

    float* sD  = &tbT[0][0];             // 1152 floats distances (alias, dead later)
    float* sRf = sD + AT * NN;           // 288 floats molecule R (1440 <= 1536)

    // ---- stage molecule R, X^T ----
    for (int t = tid; t < NN * 3; t += 256) sRf[t] = R[b * NN * 3 + t];
    if (tid < AT * FF) {
        int a = tid >> 4, f = tid & 15;
        sX[f][a] = X[(a0 + a) * FF + f];
    }
    __syncthreads();

    // ---- phase 1: distance table D[j][i] ----
    for (int e = tid; e < AT * NN; e += 256) {
        int j = e / NN, i = e - j * NN;
        float dx = sRf[i * 3 + 0] - sRf[(lbase + j) * 3 + 0];
        float dy = sRf[i * 3 + 1] - sRf[(lbase + j) * 3 + 1];
        float dz = sRf[i * 3 + 2] - sRf[(lbase + j) * 3 + 2];
        sD[e] = sqrtf(dx * dx + dy * dy + dz * dz);
    }
    __syncthreads();   // no DMA outstanding yet -> cheap

    // ---- bias preloads (named scalars; issued BEFORE the chunk DMAs so they
    //      are older in the vmcnt queue -> never interfere with counting) ----
    const float beR  = be[hh];
    const float bo1R = bo1[hh], wo2R = Wo2[hh], bo2R = bo2[0];
    const float c3R0 = c3[0 * HH + hh], c3R1 = c3[1 * HH + hh], c3R2 = c3[2 * HH + hh];
    const float ba1R0 = ba1[0 * HH + hh], ba1R1 = ba1[1 * HH + hh], ba1R2 = ba1[2 * HH + hh];
    const float ba2R0 = ba2[0 * HH + hh], ba2R1 = ba2[1 * HH + hh], ba2R2 = ba2[2 * HH + hh];

    // ---- prologue: issue chunks 0..3 (hidden under S-phase) ----
    stage16k(W3i,        wb[0], tid);    // chunk 0: W3[0] k 0-31
    stage16k(W3i + CHF,  wb[1], tid);    // chunk 1: W3[0] k 32-63
    stage16k(Wa2i,       wb[2], tid);    // chunk 2: Wa2[0] m 0-31
    stage16k(Wa2i + CHF, wb[3], tid);    // chunk 3: Wa2[0] m 32-63

    // ---- phase 2: sST[j][k] = sum_{i<nv} exp(-g*(D[j][i]-ck)^2) ----
    {
        const int k = tid & 63;
        const float ck = (float)k * (CUTOFF_F / (float)(KK - 1));
        #pragma unroll
        for (int r = 0; r < 3; ++r) {
            int j = 3 * wv + r;              // wave-uniform
            if (lbase + j >= nv) { sST[j][k] = 0.f; continue; }
            const float* Dr = sD + j * NN;
            float acc = 0.f;
            for (int i = 0; i < nv; ++i) {
                float u = Dr[i] - ck;
                acc += __expf(-GAMMA_F * u * u);
            }
            sST[j][k] = acc;
        }
    }

    // ---- embedding: h = X@We + be ----
    float h[6];
    {
        float acc[6] = {0, 0, 0, 0, 0, 0};
        const float* wp = We + hh;
        #pragma unroll
        for (int f = 0; f < FF; ++f) {
            float w = wp[f * HH];
            #pragma unroll
            for (int a = 0; a < 6; ++a) acc[a] += w * sX[f][at0 + a];
        }
        #pragma unroll
        for (int a = 0; a < 6; ++a) h[a] = acc[a] + beR;
    }

    BND("12");   // chunk 0 landed everywhere (1,2,3 still in flight)

    // ---- layers: phases 6l+0 .. 6l+5 ----
    #pragma unroll
    for (int l = 0; l < LL; ++l) {
        const float c3v  = (l == 0) ? c3R0  : (l == 1) ? c3R1  : c3R2;
        const float ba1v = (l == 0) ? ba1R0 : (l == 1) ? ba1R1 : ba1R2;
        const float ba2v = (l == 0) ? ba2R0 : (l == 1) ? ba2R1 : ba2R2;
        const float* WaN = (l < LL - 1) ? (Wa2i + (l + 1) * HH * HH) : (Wo1i + 2 * CHF);
        const float* W3N = (l < LL - 1) ? (W3i + (l + 1) * KK * HH) : Wo1i;
        const float* WaL = Wa2i + l * HH * HH;

        // GEMM1: acc = S @ W3[l]
        float acc[6] = {0, 0, 0, 0, 0, 0};
        GEMMQ6(acc, (&wb[(6 * l + 0) & 3][0]), sST, 0);       // phase 6l+0
        BND("8"); stage16k(WaL + 2 * CHF, &wb[(6 * l + 4) & 3][0], tid);
        GEMMQ6(acc, (&wb[(6 * l + 1) & 3][0]), sST, 32);      // phase 6l+1
        {   // silu -> tbT (last tbT readers finished phase 6l-1, barrier passed)
            #pragma unroll
            for (int a = 0; a < 6; ++a)
                tbT[at0 + a][hh] = silu1(acc[a] + cb * c3v + ba1v);
        }
        BND("8"); stage16k(WaL + 3 * CHF, &wb[(6 * l + 5) & 3][0], tid);

        // GEMM2: h += t @ Wa2[l]
        float acc2[6] = {0, 0, 0, 0, 0, 0};
        GEMMQ6(acc2, (&wb[(6 * l + 2) & 3][0]), tbT, 0);      // phase 6l+2
        BND("8"); stage16k(W3N, &wb[(6 * l + 6) & 3][0], tid);
        GEMMQ6(acc2, (&wb[(6 * l + 3) & 3][0]), tbT, 32);     // phase 6l+3
        BND("8"); stage16k(W3N + CHF, &wb[(6 * l + 7) & 3][0], tid);
        GEMMQ6(acc2, (&wb[(6 * l + 4) & 3][0]), tbT, 64);     // phase 6l+4
        BND("8"); stage16k(WaN, &wb[(6 * l + 8) & 3][0], tid);
        GEMMQ6(acc2, (&wb[(6 * l + 5) & 3][0]), tbT, 96);     // phase 6l+5
        #pragma unroll
        for (int a = 0; a < 6; ++a) h[a] += acc2[a] + ba2v;
        BND("8");
        stage16k((l < LL - 1) ? (Wa2i + (l + 1) * HH * HH + CHF) : (Wo1i + 3 * CHF),
                 &wb[(6 * l + 9) & 3][0], tid);
    }

    // ---- stage h into tbT for the head (tbT readers done: barrier above) ----
    #pragma unroll
    for (int a = 0; a < 6; ++a) tbT[at0 + a][hh] = h[a];
    asm volatile("s_waitcnt lgkmcnt(0)" ::: "memory");
    __builtin_amdgcn_s_barrier();
    __builtin_amdgcn_sched_barrier(0);

    // ---- output head: phases 18..21 (slots 2,3,0,1), epilogue waits 8/4/0 ----
    float acc[6] = {0, 0, 0, 0, 0, 0};
    GEMMQ6(acc, (&wb[2][0]), tbT, 0);        // phase 18
    BND("8");
    GEMMQ6(acc, (&wb[3][0]), tbT, 32);       // phase 19
    BND("4");
    GEMMQ6(acc, (&wb[0][0]), tbT, 64);       // phase 20
    BND("0");
    GEMMQ6(acc, (&wb[1][0]), tbT, 96);       // phase 21

    float p6[6];
    #pragma unroll
    for (int a = 0; a < 6; ++a) p6[a] = silu1(acc[a] + bo1R) * wo2R;
    // reduce over the 64 channel lanes of each wave
    #pragma unroll
    for (int a = 0; a < 6; ++a) {
        float r = p6[a];
        r += __shfl_down(r, 32); r += __shfl_down(r, 16);
        r += __shfl_down(r, 8);  r += __shfl_down(r, 4);
        r += __shfl_down(r, 2);  r += __shfl_down(r, 1);
        p6[a] = r;
    }
    if ((tid & 63) == 0) {
        #pragma unroll
        for (int a = 0; a < 6; ++a) po[wv][a] = p6[a];
    }
    __syncthreads();   // vmcnt already 0 -> no hidden drain cost
    if (tid == 0) {
        // atom j: half hj=j/6 -> waves 2*hj (hh 0-63) and 2*hj+1 (hh 64-127)
        float sum = 0.f;
        #pragma unroll
        for (int j = 0; j < AT; ++j) {
            if (lbase + j < nv) {
                int hj = j / 6, a = j % 6;
                sum += po[2 * hj][a] + po[2 * hj + 1][a] + bo2R;
            }
        }
        atomicAdd(out + b, sum / cb);
    }
}

extern "C" void kernel_launch(void* const* d_in, const int* in_sizes, int n_in,
                              void* d_out, int out_size, void* d_ws, size_t ws_size,
                              hipStream_t stream) {
    const float* X     = (const float*)d_in[0];
    const float* R     = (const float*)d_in[1];
    const int*   batch = (const int*)  d_in[2];
    const float* We    = (const float*)d_in[3];
    const float* be    = (const float*)d_in[4];
    const float* Wrbf  = (const float*)d_in[5];
    const float* brbf  = (const float*)d_in[6];
    const float* Wpair = (const float*)d_in[7];
    const float* bpair = (const float*)d_in[8];
    const float* Wa1   = (const float*)d_in[9];
    const float* ba1   = (const float*)d_in[10];
    const float* Wa2   = (const float*)d_in[11];
    const float* ba2   = (const float*)d_in[12];
    const float* Wo1   = (const float*)d_in[13];
    const float* bo1   = (const float*)d_in[14];
    const float* Wo2   = (const float*)d_in[15];
    const float* bo2   = (const float*)d_in[16];

    float* w    = (float*)d_ws;
    float* W3i  = w;                       // L*K*H  = 24576
    float* c3   = W3i + LL * KK * HH;      // L*H    = 384
    float* Wa2i = c3 + LL * HH;            // L*H*H  = 49152
    float* Wo1i = Wa2i + LL * HH * HH;     // H*H    = 16384
    float* cnt  = Wo1i + HH * HH;          // B      = 64
    float* out  = (float*)d_out;

    hipLaunchKernelGGL(pre_kernel,
                       dim3(W3_BLOCKS + WA2_CP + WO1_CP + CNT_BLOCKS), dim3(256),
                       0, stream, Wrbf, brbf, Wpair, bpair, Wa1, Wa2, Wo1, batch,
                       W3i, c3, Wa2i, Wo1i, cnt, out);
    hipLaunchKernelGGL(chain_kernel, dim3(BB * NN / AT), dim3(256), 0, stream,
                       X, R, We, be, ba1, ba2, bo1, Wo2, bo2,
                       W3i, Wa2i, Wo1i, c3, cnt, out);
}

// Round 14
// 57.205 us; speedup vs baseline: 1.2586x; 1.2586x over previous
//
#include <hip/hip_runtime.h>
#include <hip/hip_bf16.h>

#define BB 64
#define NN 96
#define FF 16
#define HH 128
#define KK 64
#define LL 3
#define CUTOFF_F 10.0f
#define GAMMA_F 10.0f

#define W3_BLOCKS 99
#define WA2_CP 12
#define WO1_CP 4
#define CNT_BLOCKS BB

// ---------------------------------------------------------------------------
// pre_kernel (unchanged):
//   [0,99):    W3 rows k-quad-interleaved: W3i[l][(kk>>2)*128+h][kk&3]; c3.
//   [99,111):  Wa2i = k-quad-interleaved Wa2
//   [111,115): Wo1i = k-quad-interleaved Wo1
//   [115,179): cnt[b]; zero out[b]
// ---------------------------------------------------------------------------
__global__ __launch_bounds__(256) void pre_kernel(
    const float* __restrict__ Wrbf, const float* __restrict__ brbf,
    const float* __restrict__ Wpair, const float* __restrict__ bpair,
    const float* __restrict__ Wa1, const float* __restrict__ Wa2,
    const float* __restrict__ Wo1,
    const int* __restrict__ batch,
    float* __restrict__ W3i, float* __restrict__ c3,
    float* __restrict__ Wa2i, float* __restrict__ Wo1i,
    float* __restrict__ cnt, float* __restrict__ out)
{
    const int bid = blockIdx.x;
    const int tid = threadIdx.x;
    if (bid < W3_BLOCKS) {
        __shared__ float sW2[2][HH];
        const int l    = bid / 33;
        const int r0   = (bid % 33) * 2;
        const int half = tid >> 7;
        const int h    = tid & 127;
        const int kk   = r0 + half;       // 0..65 (65 inactive)
        const bool active = (kk <= KK);
        if (active) {
            const float* Wp = Wpair + l * HH * HH + h;
            const float* arow;
            float acc;
            if (kk < KK) { arow = Wrbf + (l * KK + kk) * HH; acc = 0.f; }
            else         { arow = brbf + l * HH;             acc = bpair[l * HH + h]; }
            #pragma unroll 8
            for (int m = 0; m < HH; ++m) acc += arow[m] * Wp[m * HH];
            sW2[half][h] = acc;
        }
        __syncthreads();
        if (active) {
            const float* Wa = Wa1 + l * HH * HH + h;
            const float* row = sW2[half];
            float a3 = 0.f;
            #pragma unroll 8
            for (int m = 0; m < HH; ++m) a3 += row[m] * Wa[m * HH];
            if (kk < KK)
                W3i[l * KK * HH + (((kk >> 2) * HH + h) << 2) + (kk & 3)] = a3;
            else
                c3[l * HH + h] = a3;
        }
    } else if (bid < W3_BLOCKS + WA2_CP + WO1_CP) {
        int ci = bid - W3_BLOCKS;
        const float* src;
        float* dst;
        if (ci < WA2_CP) { src = Wa2 + ci * 4096; dst = Wa2i + ci * 4096; }
        else             { src = Wo1 + (ci - WA2_CP) * 4096; dst = Wo1i + (ci - WA2_CP) * 4096; }
        for (int e = tid; e < 4096; e += 256) {
            int k = e >> 7, h = e & 127;
            dst[(((k >> 2) * HH + h) << 2) + (k & 3)] = src[e];
        }
    } else {
        int b = bid - (W3_BLOCKS + WA2_CP + WO1_CP);
        __shared__ int c[4];
        bool v = (tid < NN) && (batch[b * NN + tid] != -1);
        unsigned long long m = __ballot(v);
        if ((tid & 63) == 0) c[tid >> 6] = __popcll(m);
        __syncthreads();
        if (tid == 0) {
            cnt[b] = (float)(c[0] + c[1] + c[2] + c[3]);
            out[b] = 0.f;
        }
    }
}

// ---------------------------------------------------------------------------
// chain_kernel: identical to R13 EXCEPT the layer loop is NOT unrolled
// (R13's #pragma unroll tripled live ranges -> ~480B/thread scratch spills ->
// 63MB WRITE / 34MB FETCH pathology). Ring: 4-slot x 16KB, counted vmcnt(8),
// one raw s_barrier per phase, stage-after-barrier, epilogue 8/4/0.
// ---------------------------------------------------------------------------
#define AT 12
#define CHF 4096              // floats per 16KB chunk (32 k x 128 ch quad-interleaved)
#define SSW 64                // sST row stride
#define TBW 128               // tbT row stride

typedef const __attribute__((address_space(1))) void* gp1_t;
typedef __attribute__((address_space(3))) void* lp3_t;

__device__ __forceinline__ void stage16k(const float* g, float* lds, int tid)
{
    const int lane = tid & 63, wvq = tid >> 6;
    #pragma unroll
    for (int j = 0; j < 4; ++j) {
        const int base = j * 256 + wvq * 64;           // float4 units
        __builtin_amdgcn_global_load_lds((gp1_t)(g + (size_t)(base + lane) * 4),
                                         (lp3_t)(lds + (size_t)base * 4), 16, 0, 0);
    }
}

// phase boundary: publish loads (vmcnt<=N) + flush LDS writes, then barrier.
#define BND(VM) do {                                                        \
    asm volatile("s_waitcnt vmcnt(" VM ") lgkmcnt(0)" ::: "memory");        \
    __builtin_amdgcn_s_barrier();                                           \
    __builtin_amdgcn_sched_barrier(0);                                      \
} while (0)

__device__ __forceinline__ float silu1(float v) { return v / (1.f + __expf(-v)); }

// one 16KB chunk (32 k) of a GEMM: 8 quad-groups; 6 atoms; 24 FMA per group
#define GEMMQ6(ACC, WBP, SRC, KB) do {                                      \
    _Pragma("unroll")                                                       \
    for (int g5 = 0; g5 < 8; ++g5) {                                        \
        float4 w4 = *(const float4*)&(WBP)[(g5 * HH + hh) << 2];            \
        float4 u0 = *(const float4*)&SRC[at0 + 0][(KB) + g5 * 4];           \
        float4 u1 = *(const float4*)&SRC[at0 + 1][(KB) + g5 * 4];           \
        float4 u2 = *(const float4*)&SRC[at0 + 2][(KB) + g5 * 4];           \
        float4 u3 = *(const float4*)&SRC[at0 + 3][(KB) + g5 * 4];           \
        float4 u4 = *(const float4*)&SRC[at0 + 4][(KB) + g5 * 4];           \
        float4 u5 = *(const float4*)&SRC[at0 + 5][(KB) + g5 * 4];           \
        ACC[0] += w4.x*u0.x + w4.y*u0.y + w4.z*u0.z + w4.w*u0.w;            \
        ACC[1] += w4.x*u1.x + w4.y*u1.y + w4.z*u1.z + w4.w*u1.w;            \
        ACC[2] += w4.x*u2.x + w4.y*u2.y + w4.z*u2.z + w4.w*u2.w;            \
        ACC[3] += w4.x*u3.x + w4.y*u3.y + w4.z*u3.z + w4.w*u3.w;            \
        ACC[4] += w4.x*u4.x + w4.y*u4.y + w4.z*u4.z + w4.w*u4.w;            \
        ACC[5] += w4.x*u5.x + w4.y*u5.y + w4.z*u5.z + w4.w*u5.w;            \
    }                                                                       \
} while (0)

__global__ __launch_bounds__(256, 2) void chain_kernel(
    const float* __restrict__ X, const float* __restrict__ R,
    const float* __restrict__ We, const float* __restrict__ be,
    const float* __restrict__ ba1, const float* __restrict__ ba2,
    const float* __restrict__ bo1, const float* __restrict__ Wo2,
    const float* __restrict__ bo2, const float* __restrict__ W3i,
    const float* __restrict__ Wa2i, const float* __restrict__ Wo1i,
    const float* __restrict__ c3, const float* __restrict__ cnt,
    float* __restrict__ out)
{
    __shared__ __align__(16) float wb[4][CHF];     // 64KB weight ring
    __shared__ __align__(16) float sST[AT][SSW];   // 3KB S, atom-major (persists)
    __shared__ __align__(16) float tbT[AT][TBW];   // 6KB t / h (sD/sRf alias early)
    __shared__ __align__(16) float sX[FF][AT];     // 0.75KB
    __shared__ float po[4][6];

    const int tid  = threadIdx.x;
    const int hh   = tid & 127;          // channel
    const int half = tid >> 7;           // atom half
    const int wv   = tid >> 6;           // wave 0..3
    const int at0  = half * 6;           // this thread's atoms at0..at0+5
    const int a0   = blockIdx.x * AT;    // 96 % 12 == 0 -> block within one molecule
    const int b    = a0 / NN;
    const int lbase = a0 - b * NN;       // molecule-local first atom
    const float cb = cnt[b];
    const int nv   = (int)cb;            // valid atoms = molecule-local prefix

    float* sD  = &tbT[0][0];             // 1152 floats distances (alias, dead later)
    float* sRf = sD + AT * NN;           // 288 floats molecule R (1440 <= 1536)

    // ---- stage molecule R, X^T ----
    for (int t = tid; t < NN * 3; t += 256) sRf[t] = R[b * NN * 3 + t];
    if (tid < AT * FF) {
        int a = tid >> 4, f = tid & 15;
        sX[f][a] = X[(a0 + a) * FF + f];
    }
    __syncthreads();

    // ---- phase 1: distance table D[j][i] ----
    for (int e = tid; e < AT * NN; e += 256) {
        int j = e / NN, i = e - j * NN;
        float dx = sRf[i * 3 + 0] - sRf[(lbase + j) * 3 + 0];
        float dy = sRf[i * 3 + 1] - sRf[(lbase + j) * 3 + 1];
        float dz = sRf[i * 3 + 2] - sRf[(lbase + j) * 3 + 2];
        sD[e] = sqrtf(dx * dx + dy * dy + dz * dz);
    }
    __syncthreads();   // no DMA outstanding yet -> cheap

    // ---- bias preloads (named scalars, BEFORE chunk DMAs -> older in queue) ----
    const float beR  = be[hh];
    const float bo1R = bo1[hh], wo2R = Wo2[hh], bo2R = bo2[0];
    const float c3R0 = c3[0 * HH + hh], c3R1 = c3[1 * HH + hh], c3R2 = c3[2 * HH + hh];
    const float ba1R0 = ba1[0 * HH + hh], ba1R1 = ba1[1 * HH + hh], ba1R2 = ba1[2 * HH + hh];
    const float ba2R0 = ba2[0 * HH + hh], ba2R1 = ba2[1 * HH + hh], ba2R2 = ba2[2 * HH + hh];

    // ---- prologue: issue chunks 0..3 (hidden under S-phase) ----
    stage16k(W3i,        wb[0], tid);    // chunk 0: W3[0] k 0-31
    stage16k(W3i + CHF,  wb[1], tid);    // chunk 1: W3[0] k 32-63
    stage16k(Wa2i,       wb[2], tid);    // chunk 2: Wa2[0] m 0-31
    stage16k(Wa2i + CHF, wb[3], tid);    // chunk 3: Wa2[0] m 32-63

    // ---- phase 2: sST[j][k] = sum_{i<nv} exp(-g*(D[j][i]-ck)^2) ----
    {
        const int k = tid & 63;
        const float ck = (float)k * (CUTOFF_F / (float)(KK - 1));
        #pragma unroll
        for (int r = 0; r < 3; ++r) {
            int j = 3 * wv + r;              // wave-uniform
            if (lbase + j >= nv) { sST[j][k] = 0.f; continue; }
            const float* Dr = sD + j * NN;
            float acc = 0.f;
            for (int i = 0; i < nv; ++i) {
                float u = Dr[i] - ck;
                acc += __expf(-GAMMA_F * u * u);
            }
            sST[j][k] = acc;
        }
    }

    // ---- embedding: h = X@We + be ----
    float h[6];
    {
        float acc[6] = {0, 0, 0, 0, 0, 0};
        const float* wp = We + hh;
        #pragma unroll
        for (int f = 0; f < FF; ++f) {
            float w = wp[f * HH];
            #pragma unroll
            for (int a = 0; a < 6; ++a) acc[a] += w * sX[f][at0 + a];
        }
        #pragma unroll
        for (int a = 0; a < 6; ++a) h[a] = acc[a] + beR;
    }

    BND("12");   // chunk 0 landed everywhere (1,2,3 still in flight)

    // ---- layers: phases 6l+0 .. 6l+5 (NOT unrolled -> no spills) ----
    #pragma unroll 1
    for (int l = 0; l < LL; ++l) {
        const float c3v  = (l == 0) ? c3R0  : (l == 1) ? c3R1  : c3R2;
        const float ba1v = (l == 0) ? ba1R0 : (l == 1) ? ba1R1 : ba1R2;
        const float ba2v = (l == 0) ? ba2R0 : (l == 1) ? ba2R1 : ba2R2;
        const float* WaN = (l < LL - 1) ? (Wa2i + (l + 1) * HH * HH) : (Wo1i + 2 * CHF);
        const float* W3N = (l < LL - 1) ? (W3i + (l + 1) * KK * HH) : Wo1i;
        const float* WaL = Wa2i + l * HH * HH;

        // GEMM1: acc = S @ W3[l]
        float acc[6] = {0, 0, 0, 0, 0, 0};
        GEMMQ6(acc, (&wb[(6 * l + 0) & 3][0]), sST, 0);       // phase 6l+0
        BND("8"); stage16k(WaL + 2 * CHF, &wb[(6 * l + 4) & 3][0], tid);
        GEMMQ6(acc, (&wb[(6 * l + 1) & 3][0]), sST, 32);      // phase 6l+1
        {   // silu -> tbT (last tbT readers finished before previous barrier)
            #pragma unroll
            for (int a = 0; a < 6; ++a)
                tbT[at0 + a][hh] = silu1(acc[a] + cb * c3v + ba1v);
        }
        BND("8"); stage16k(WaL + 3 * CHF, &wb[(6 * l + 5) & 3][0], tid);

        // GEMM2: h += t @ Wa2[l]
        float acc2[6] = {0, 0, 0, 0, 0, 0};
        GEMMQ6(acc2, (&wb[(6 * l + 2) & 3][0]), tbT, 0);      // phase 6l+2
        BND("8"); stage16k(W3N, &wb[(6 * l + 6) & 3][0], tid);
        GEMMQ6(acc2, (&wb[(6 * l + 3) & 3][0]), tbT, 32);     // phase 6l+3
        BND("8"); stage16k(W3N + CHF, &wb[(6 * l + 7) & 3][0], tid);
        GEMMQ6(acc2, (&wb[(6 * l + 4) & 3][0]), tbT, 64);     // phase 6l+4
        BND("8"); stage16k(WaN, &wb[(6 * l + 8) & 3][0], tid);
        GEMMQ6(acc2, (&wb[(6 * l + 5) & 3][0]), tbT, 96);     // phase 6l+5
        #pragma unroll
        for (int a = 0; a < 6; ++a) h[a] += acc2[a] + ba2v;
        BND("8");
        stage16k((l < LL - 1) ? (Wa2i + (l + 1) * HH * HH + CHF) : (Wo1i + 3 * CHF),
                 &wb[(6 * l + 9) & 3][0], tid);
    }

    // ---- stage h into tbT for the head ----
    #pragma unroll
    for (int a = 0; a < 6; ++a) tbT[at0 + a][hh] = h[a];
    asm volatile("s_waitcnt lgkmcnt(0)" ::: "memory");
    __builtin_amdgcn_s_barrier();
    __builtin_amdgcn_sched_barrier(0);

    // ---- output head: phases 18..21 (slots 2,3,0,1), epilogue waits 8/4/0 ----
    float acc[6] = {0, 0, 0, 0, 0, 0};
    GEMMQ6(acc, (&wb[2][0]), tbT, 0);        // phase 18
    BND("8");
    GEMMQ6(acc, (&wb[3][0]), tbT, 32);       // phase 19
    BND("4");
    GEMMQ6(acc, (&wb[0][0]), tbT, 64);       // phase 20
    BND("0");
    GEMMQ6(acc, (&wb[1][0]), tbT, 96);       // phase 21

    float p6[6];
    #pragma unroll
    for (int a = 0; a < 6; ++a) p6[a] = silu1(acc[a] + bo1R) * wo2R;
    // reduce over the 64 channel lanes of each wave
    #pragma unroll
    for (int a = 0; a < 6; ++a) {
        float r = p6[a];
        r += __shfl_down(r, 32); r += __shfl_down(r, 16);
        r += __shfl_down(r, 8);  r += __shfl_down(r, 4);
        r += __shfl_down(r, 2);  r += __shfl_down(r, 1);
        p6[a] = r;
    }
    if ((tid & 63) == 0) {
        #pragma unroll
        for (int a = 0; a < 6; ++a) po[wv][a] = p6[a];
    }
    __syncthreads();   // vmcnt already 0 -> no hidden drain cost
    if (tid == 0) {
        // atom j: half hj=j/6 -> waves 2*hj (hh 0-63) and 2*hj+1 (hh 64-127)
        float sum = 0.f;
        #pragma unroll
        for (int j = 0; j < AT; ++j) {
            if (lbase + j < nv) {
                int hj = j / 6, a = j % 6;
                sum += po[2 * hj][a] + po[2 * hj + 1][a] + bo2R;
            }
        }
        atomicAdd(out + b, sum / cb);
    }
}

extern "C" void kernel_launch(void* const* d_in, const int* in_sizes, int n_in,
                              void* d_out, int out_size, void* d_ws, size_t ws_size,
                              hipStream_t stream) {
    const float* X     = (const float*)d_in[0];
    const float* R     = (const float*)d_in[1];
    const int*   batch = (const int*)  d_in[2];
    const float* We    = (const float*)d_in[3];
    const float* be    = (const float*)d_in[4];
    const float* Wrbf  = (const float*)d_in[5];
    const float* brbf  = (const float*)d_in[6];
    const float* Wpair = (const float*)d_in[7];
    const float* bpair = (const float*)d_in[8];
    const float* Wa1   = (const float*)d_in[9];
    const float* ba1   = (const float*)d_in[10];
    const float* Wa2   = (const float*)d_in[11];
    const float* ba2   = (const float*)d_in[12];
    const float* Wo1   = (const float*)d_in[13];
    const float* bo1   = (const float*)d_in[14];
    const float* Wo2   = (const float*)d_in[15];
    const float* bo2   = (const float*)d_in[16];

    float* w    = (float*)d_ws;
    float* W3i  = w;                       // L*K*H  = 24576
    float* c3   = W3i + LL * KK * HH;      // L*H    = 384
    float* Wa2i = c3 + LL * HH;            // L*H*H  = 49152
    float* Wo1i = Wa2i + LL * HH * HH;     // H*H    = 16384
    float* cnt  = Wo1i + HH * HH;          // B      = 64
    float* out  = (float*)d_out;

    hipLaunchKernelGGL(pre_kernel,
                       dim3(W3_BLOCKS + WA2_CP + WO1_CP + CNT_BLOCKS), dim3(256),
                       0, stream, Wrbf, brbf, Wpair, bpair, Wa1, Wa2, Wo1, batch,
                       W3i, c3, Wa2i, Wo1i, cnt, out);
    hipLaunchKernelGGL(chain_kernel, dim3(BB * NN / AT), dim3(256), 0, stream,
                       X, R, We, be, ba1, ba2, bo1, Wo2, bo2,
                       W3i, Wa2i, Wo1i, c3, cnt, out);
}

// Round 15
// 51.358 us; speedup vs baseline: 1.4019x; 1.1138x over previous
//
#include <hip/hip_runtime.h>
#include <hip/hip_bf16.h>

#define BB 64
#define NN 96
#define FF 16
#define HH 128
#define KK 64
#define LL 3
#define CUTOFF_F 10.0f
#define GAMMA_F 10.0f

#define W3_BLOCKS 99
#define WA2_CP 12
#define WO1_CP 4
#define CNT_BLOCKS BB

// ---------------------------------------------------------------------------
// pre_kernel: weights stored PAIR-INTERLEAVED per 16KB chunk (32k x 128ch):
//   within chunk: idx = ((k>>1)*64 + (h>>1))*4 + (k&1)*2 + (h&1)
//   -> one b128 per lane = {w[k][c0], w[k][c0+1], w[k+1][c0], w[k+1][c0+1]}
//   [0,99):    W3 rows (row 64 -> c3)   [99,111): Wa2i   [111,115): Wo1i
//   [115,179): cnt[b]; zero out[b]
// ---------------------------------------------------------------------------
__global__ __launch_bounds__(256) void pre_kernel(
    const float* __restrict__ Wrbf, const float* __restrict__ brbf,
    const float* __restrict__ Wpair, const float* __restrict__ bpair,
    const float* __restrict__ Wa1, const float* __restrict__ Wa2,
    const float* __restrict__ Wo1,
    const int* __restrict__ batch,
    float* __restrict__ W3i, float* __restrict__ c3,
    float* __restrict__ Wa2i, float* __restrict__ Wo1i,
    float* __restrict__ cnt, float* __restrict__ out)
{
    const int bid = blockIdx.x;
    const int tid = threadIdx.x;
    if (bid < W3_BLOCKS) {
        __shared__ float sW2[2][HH];
        const int l    = bid / 33;
        const int r0   = (bid % 33) * 2;
        const int half = tid >> 7;
        const int h    = tid & 127;
        const int kk   = r0 + half;       // 0..65 (65 inactive)
        const bool active = (kk <= KK);
        if (active) {
            const float* Wp = Wpair + l * HH * HH + h;
            const float* arow;
            float acc;
            if (kk < KK) { arow = Wrbf + (l * KK + kk) * HH; acc = 0.f; }
            else         { arow = brbf + l * HH;             acc = bpair[l * HH + h]; }
            #pragma unroll 8
            for (int m = 0; m < HH; ++m) acc += arow[m] * Wp[m * HH];
            sW2[half][h] = acc;
        }
        __syncthreads();
        if (active) {
            const float* Wa = Wa1 + l * HH * HH + h;
            const float* row = sW2[half];
            float a3 = 0.f;
            #pragma unroll 8
            for (int m = 0; m < HH; ++m) a3 += row[m] * Wa[m * HH];
            if (kk < KK) {
                int kc = kk & 31, ch = kk >> 5;   // chunk 0/1 within layer
                W3i[l * KK * HH + ch * 4096 +
                    (((kc >> 1) * 64 + (h >> 1)) << 2) + ((kc & 1) << 1) + (h & 1)] = a3;
            } else {
                c3[l * HH + h] = a3;
            }
        }
    } else if (bid < W3_BLOCKS + WA2_CP + WO1_CP) {
        int ci = bid - W3_BLOCKS;
        const float* src;
        float* dst;
        if (ci < WA2_CP) { src = Wa2 + ci * 4096; dst = Wa2i + ci * 4096; }
        else             { src = Wo1 + (ci - WA2_CP) * 4096; dst = Wo1i + (ci - WA2_CP) * 4096; }
        for (int e = tid; e < 4096; e += 256) {
            int k = e >> 7, h = e & 127;
            dst[(((k >> 1) * 64 + (h >> 1)) << 2) + ((k & 1) << 1) + (h & 1)] = src[e];
        }
    } else {
        int b = bid - (W3_BLOCKS + WA2_CP + WO1_CP);
        __shared__ int c[4];
        bool v = (tid < NN) && (batch[b * NN + tid] != -1);
        unsigned long long m = __ballot(v);
        if ((tid & 63) == 0) c[tid >> 6] = __popcll(m);
        __syncthreads();
        if (tid == 0) {
            cnt[b] = (float)(c[0] + c[1] + c[2] + c[3]);
            out[b] = 0.f;
        }
    }
}

// ---------------------------------------------------------------------------
// chain_kernel: R14 skeleton (AT=12, 256 thr, grid 512 = 2 blocks/CU; 4-slot
// 16KB ring; counted vmcnt(8); one s_barrier/phase; stage-after-barrier;
// epilogue 8/4/0) with a 2ch x 3at thread tile: lane q -> channels 2q,2q+1;
// wave wv -> atoms 3wv..3wv+2. Per 4-k group: 2 weight b128 (pair-interleave,
// conflict-free) + 3 operand broadcasts = 5 LDS reads / 24 FMA (was 7/24).
// ---------------------------------------------------------------------------
#define AT 12
#define CHF 4096              // floats per 16KB chunk
#define SSW 64                // sST row stride
#define TBW 128               // tbT row stride

typedef const __attribute__((address_space(1))) void* gp1_t;
typedef __attribute__((address_space(3))) void* lp3_t;

__device__ __forceinline__ void stage16k(const float* g, float* lds, int tid)
{
    const int lane = tid & 63, wvq = tid >> 6;
    #pragma unroll
    for (int j = 0; j < 4; ++j) {
        const int base = j * 256 + wvq * 64;           // float4 units
        __builtin_amdgcn_global_load_lds((gp1_t)(g + (size_t)(base + lane) * 4),
                                         (lp3_t)(lds + (size_t)base * 4), 16, 0, 0);
    }
}

// phase boundary: publish loads (vmcnt<=N) + flush LDS writes, then barrier.
#define BND(VM) do {                                                        \
    asm volatile("s_waitcnt vmcnt(" VM ") lgkmcnt(0)" ::: "memory");        \
    __builtin_amdgcn_s_barrier();                                           \
    __builtin_amdgcn_sched_barrier(0);                                      \
} while (0)

__device__ __forceinline__ float silu1(float v) { return v / (1.f + __expf(-v)); }

// one 16KB chunk (32 k) of a GEMM. ACC[a*2+c]: atom a (0..2), channel c (0..1)
#define GEMMP(ACC, WBP, SRC, KB) do {                                       \
    _Pragma("unroll")                                                       \
    for (int g5 = 0; g5 < 8; ++g5) {                                        \
        float4 wa  = *(const float4*)&(WBP)[(g5 * 128 + q) << 2];           \
        float4 wbv = *(const float4*)&(WBP)[(g5 * 128 + 64 + q) << 2];      \
        float4 u0 = *(const float4*)&SRC[at0 + 0][(KB) + g5 * 4];           \
        float4 u1 = *(const float4*)&SRC[at0 + 1][(KB) + g5 * 4];           \
        float4 u2 = *(const float4*)&SRC[at0 + 2][(KB) + g5 * 4];           \
        ACC[0] += wa.x*u0.x + wa.z*u0.y + wbv.x*u0.z + wbv.z*u0.w;          \
        ACC[1] += wa.y*u0.x + wa.w*u0.y + wbv.y*u0.z + wbv.w*u0.w;          \
        ACC[2] += wa.x*u1.x + wa.z*u1.y + wbv.x*u1.z + wbv.z*u1.w;          \
        ACC[3] += wa.y*u1.x + wa.w*u1.y + wbv.y*u1.z + wbv.w*u1.w;          \
        ACC[4] += wa.x*u2.x + wa.z*u2.y + wbv.x*u2.z + wbv.z*u2.w;          \
        ACC[5] += wa.y*u2.x + wa.w*u2.y + wbv.y*u2.z + wbv.w*u2.w;          \
    }                                                                       \
} while (0)

__global__ __launch_bounds__(256, 2) void chain_kernel(
    const float* __restrict__ X, const float* __restrict__ R,
    const float* __restrict__ We, const float* __restrict__ be,
    const float* __restrict__ ba1, const float* __restrict__ ba2,
    const float* __restrict__ bo1, const float* __restrict__ Wo2,
    const float* __restrict__ bo2, const float* __restrict__ W3i,
    const float* __restrict__ Wa2i, const float* __restrict__ Wo1i,
    const float* __restrict__ c3, const float* __restrict__ cnt,
    float* __restrict__ out)
{
    __shared__ __align__(16) float wb[4][CHF];     // 64KB weight ring
    __shared__ __align__(16) float sST[AT][SSW];   // 3KB S, atom-major (persists)
    __shared__ __align__(16) float tbT[AT][TBW];   // 6KB t / h (sD/sRf alias early)
    __shared__ __align__(16) float sX[FF][AT];     // 0.75KB
    __shared__ float po[4][3];

    const int tid  = threadIdx.x;
    const int q    = tid & 63;           // lane: channel pair c0=2q, c0+1
    const int wv   = tid >> 6;           // wave 0..3
    const int c0   = 2 * q;
    const int at0  = 3 * wv;             // this wave's atoms at0..at0+2
    const int a0   = blockIdx.x * AT;    // 96 % 12 == 0 -> block within one molecule
    const int b    = a0 / NN;
    const int lbase = a0 - b * NN;       // molecule-local first atom
    const float cb = cnt[b];
    const int nv   = (int)cb;            // valid atoms = molecule-local prefix

    float* sD  = &tbT[0][0];             // 1152 floats distances (alias, dead later)
    float* sRf = sD + AT * NN;           // 288 floats molecule R (1440 <= 1536)

    // ---- stage molecule R, X^T ----
    for (int t = tid; t < NN * 3; t += 256) sRf[t] = R[b * NN * 3 + t];
    if (tid < AT * FF) {
        int a = tid >> 4, f = tid & 15;
        sX[f][a] = X[(a0 + a) * FF + f];
    }
    __syncthreads();

    // ---- phase 1: distance table D[j][i] ----
    for (int e = tid; e < AT * NN; e += 256) {
        int j = e / NN, i = e - j * NN;
        float dx = sRf[i * 3 + 0] - sRf[(lbase + j) * 3 + 0];
        float dy = sRf[i * 3 + 1] - sRf[(lbase + j) * 3 + 1];
        float dz = sRf[i * 3 + 2] - sRf[(lbase + j) * 3 + 2];
        sD[e] = sqrtf(dx * dx + dy * dy + dz * dz);
    }
    __syncthreads();   // no DMA outstanding yet -> cheap

    // ---- bias preloads (named scalars, BEFORE chunk DMAs -> older in queue) ----
    const float2 beR  = *(const float2*)&be[c0];
    const float2 bo1R = *(const float2*)&bo1[c0];
    const float2 wo2R = *(const float2*)&Wo2[c0];
    const float  bo2R = bo2[0];
    const float2 c3R0 = *(const float2*)&c3[0 * HH + c0];
    const float2 c3R1 = *(const float2*)&c3[1 * HH + c0];
    const float2 c3R2 = *(const float2*)&c3[2 * HH + c0];
    const float2 ba1R0 = *(const float2*)&ba1[0 * HH + c0];
    const float2 ba1R1 = *(const float2*)&ba1[1 * HH + c0];
    const float2 ba1R2 = *(const float2*)&ba1[2 * HH + c0];
    const float2 ba2R0 = *(const float2*)&ba2[0 * HH + c0];
    const float2 ba2R1 = *(const float2*)&ba2[1 * HH + c0];
    const float2 ba2R2 = *(const float2*)&ba2[2 * HH + c0];

    // ---- prologue: issue chunks 0..3 (hidden under S-phase) ----
    stage16k(W3i,        wb[0], tid);    // chunk 0: W3[0] k 0-31
    stage16k(W3i + CHF,  wb[1], tid);    // chunk 1: W3[0] k 32-63
    stage16k(Wa2i,       wb[2], tid);    // chunk 2: Wa2[0] m 0-31
    stage16k(Wa2i + CHF, wb[3], tid);    // chunk 3: Wa2[0] m 32-63

    // ---- phase 2: sST[j][k] = sum_{i<nv} exp(-g*(D[j][i]-ck)^2) ----
    {
        const int k = tid & 63;
        const float ck = (float)k * (CUTOFF_F / (float)(KK - 1));
        #pragma unroll
        for (int r = 0; r < 3; ++r) {
            int j = 3 * wv + r;              // wave-uniform; == at0+r
            if (lbase + j >= nv) { sST[j][k] = 0.f; continue; }
            const float* Dr = sD + j * NN;
            float acc = 0.f;
            for (int i = 0; i < nv; ++i) {
                float u = Dr[i] - ck;
                acc += __expf(-GAMMA_F * u * u);
            }
            sST[j][k] = acc;
        }
    }

    // ---- embedding: h[a*2+c] = X@We + be ----
    float h[6];
    {
        float acc[6] = {0, 0, 0, 0, 0, 0};
        const float* wp = We + c0;
        #pragma unroll
        for (int f = 0; f < FF; ++f) {
            float2 w2 = *(const float2*)&wp[f * HH];
            #pragma unroll
            for (int a = 0; a < 3; ++a) {
                float x = sX[f][at0 + a];
                acc[2 * a + 0] += w2.x * x;
                acc[2 * a + 1] += w2.y * x;
            }
        }
        #pragma unroll
        for (int a = 0; a < 3; ++a) {
            h[2 * a + 0] = acc[2 * a + 0] + beR.x;
            h[2 * a + 1] = acc[2 * a + 1] + beR.y;
        }
    }

    BND("12");   // chunk 0 landed everywhere (1,2,3 still in flight)

    // ---- layers: phases 6l+0 .. 6l+5 (NOT unrolled -> no spills) ----
    #pragma unroll 1
    for (int l = 0; l < LL; ++l) {
        const float2 c3v  = (l == 0) ? c3R0  : (l == 1) ? c3R1  : c3R2;
        const float2 ba1v = (l == 0) ? ba1R0 : (l == 1) ? ba1R1 : ba1R2;
        const float2 ba2v = (l == 0) ? ba2R0 : (l == 1) ? ba2R1 : ba2R2;
        const float* WaN = (l < LL - 1) ? (Wa2i + (l + 1) * HH * HH) : (Wo1i + 2 * CHF);
        const float* W3N = (l < LL - 1) ? (W3i + (l + 1) * KK * HH) : Wo1i;
        const float* WaL = Wa2i + l * HH * HH;

        // GEMM1: acc = S @ W3[l]
        float acc[6] = {0, 0, 0, 0, 0, 0};
        GEMMP(acc, (&wb[(6 * l + 0) & 3][0]), sST, 0);        // phase 6l+0
        BND("8"); stage16k(WaL + 2 * CHF, &wb[(6 * l + 4) & 3][0], tid);
        GEMMP(acc, (&wb[(6 * l + 1) & 3][0]), sST, 32);       // phase 6l+1
        {   // silu -> tbT (owned (ch-pair, atom) cells; last readers done)
            #pragma unroll
            for (int a = 0; a < 3; ++a) {
                float2 t2;
                t2.x = silu1(acc[2 * a + 0] + cb * c3v.x + ba1v.x);
                t2.y = silu1(acc[2 * a + 1] + cb * c3v.y + ba1v.y);
                *(float2*)&tbT[at0 + a][c0] = t2;
            }
        }
        BND("8"); stage16k(WaL + 3 * CHF, &wb[(6 * l + 5) & 3][0], tid);

        // GEMM2: h += t @ Wa2[l]
        float acc2[6] = {0, 0, 0, 0, 0, 0};
        GEMMP(acc2, (&wb[(6 * l + 2) & 3][0]), tbT, 0);       // phase 6l+2
        BND("8"); stage16k(W3N, &wb[(6 * l + 6) & 3][0], tid);
        GEMMP(acc2, (&wb[(6 * l + 3) & 3][0]), tbT, 32);      // phase 6l+3
        BND("8"); stage16k(W3N + CHF, &wb[(6 * l + 7) & 3][0], tid);
        GEMMP(acc2, (&wb[(6 * l + 4) & 3][0]), tbT, 64);      // phase 6l+4
        BND("8"); stage16k(WaN, &wb[(6 * l + 8) & 3][0], tid);
        GEMMP(acc2, (&wb[(6 * l + 5) & 3][0]), tbT, 96);      // phase 6l+5
        #pragma unroll
        for (int a = 0; a < 3; ++a) {
            h[2 * a + 0] += acc2[2 * a + 0] + ba2v.x;
            h[2 * a + 1] += acc2[2 * a + 1] + ba2v.y;
        }
        BND("8");
        stage16k((l < LL - 1) ? (Wa2i + (l + 1) * HH * HH + CHF) : (Wo1i + 3 * CHF),
                 &wb[(6 * l + 9) & 3][0], tid);
    }

    // ---- stage h into tbT for the head ----
    #pragma unroll
    for (int a = 0; a < 3; ++a)
        *(float2*)&tbT[at0 + a][c0] = make_float2(h[2 * a + 0], h[2 * a + 1]);
    asm volatile("s_waitcnt lgkmcnt(0)" ::: "memory");
    __builtin_amdgcn_s_barrier();
    __builtin_amdgcn_sched_barrier(0);

    // ---- output head: phases 18..21 (slots 2,3,0,1), epilogue waits 8/4/0 ----
    float acc[6] = {0, 0, 0, 0, 0, 0};
    GEMMP(acc, (&wb[2][0]), tbT, 0);         // phase 18
    BND("8");
    GEMMP(acc, (&wb[3][0]), tbT, 32);        // phase 19
    BND("4");
    GEMMP(acc, (&wb[0][0]), tbT, 64);        // phase 20
    BND("0");
    GEMMP(acc, (&wb[1][0]), tbT, 96);        // phase 21

    // per-atom partial over this lane's 2 channels; wave covers all 128
    float p3[3];
    #pragma unroll
    for (int a = 0; a < 3; ++a) {
        p3[a] = silu1(acc[2 * a + 0] + bo1R.x) * wo2R.x
              + silu1(acc[2 * a + 1] + bo1R.y) * wo2R.y;
    }
    #pragma unroll
    for (int a = 0; a < 3; ++a) {
        float r = p3[a];
        r += __shfl_down(r, 32); r += __shfl_down(r, 16);
        r += __shfl_down(r, 8);  r += __shfl_down(r, 4);
        r += __shfl_down(r, 2);  r += __shfl_down(r, 1);
        p3[a] = r;
    }
    if (q == 0) {
        #pragma unroll
        for (int a = 0; a < 3; ++a) po[wv][a] = p3[a];   // atom at0+a fully reduced
    }
    __syncthreads();   // vmcnt already 0 -> no hidden drain cost
    if (tid == 0) {
        float sum = 0.f;
        #pragma unroll
        for (int j = 0; j < AT; ++j) {
            if (lbase + j < nv) sum += po[j / 3][j % 3] + bo2R;
        }
        atomicAdd(out + b, sum / cb);
    }
}

extern "C" void kernel_launch(void* const* d_in, const int* in_sizes, int n_in,
                              void* d_out, int out_size, void* d_ws, size_t ws_size,
                              hipStream_t stream) {
    const float* X     = (const float*)d_in[0];
    const float* R     = (const float*)d_in[1];
    const int*   batch = (const int*)  d_in[2];
    const float* We    = (const float*)d_in[3];
    const float* be    = (const float*)d_in[4];
    const float* Wrbf  = (const float*)d_in[5];
    const float* brbf  = (const float*)d_in[6];
    const float* Wpair = (const float*)d_in[7];
    const float* bpair = (const float*)d_in[8];
    const float* Wa1   = (const float*)d_in[9];
    const float* ba1   = (const float*)d_in[10];
    const float* Wa2   = (const float*)d_in[11];
    const float* ba2   = (const float*)d_in[12];
    const float* Wo1   = (const float*)d_in[13];
    const float* bo1   = (const float*)d_in[14];
    const float* Wo2   = (const float*)d_in[15];
    const float* bo2   = (const float*)d_in[16];

    float* w    = (float*)d_ws;
    float* W3i  = w;                       // L*K*H  = 24576
    float* c3   = W3i + LL * KK * HH;      // L*H    = 384
    float* Wa2i = c3 + LL * HH;            // L*H*H  = 49152
    float* Wo1i = Wa2i + LL * HH * HH;     // H*H    = 16384
    float* cnt  = Wo1i + HH * HH;          // B      = 64
    float* out  = (float*)d_out;

    hipLaunchKernelGGL(pre_kernel,
                       dim3(W3_BLOCKS + WA2_CP + WO1_CP + CNT_BLOCKS), dim3(256),
                       0, stream, Wrbf, brbf, Wpair, bpair, Wa1, Wa2, Wo1, batch,
                       W3i, c3, Wa2i, Wo1i, cnt, out);
    hipLaunchKernelGGL(chain_kernel, dim3(BB * NN / AT), dim3(256), 0, stream,
                       X, R, We, be, ba1, ba2, bo1, Wo2, bo2,
                       W3i, Wa2i, Wo1i, c3, cnt, out);
}